// Round 4
// baseline (217.128 us; speedup 1.0000x reference)
//
#include <hip/hip_runtime.h>

// SetEq4to4: out[n,so,i,j,k,l] = sum over 69 basis ops (A,B) + bias.
// n=2, d=8, so=8, N=32, basis=69.
//
// 4-kernel pipeline:
//   memset: zero r23/r2/r3 (one contiguous 68 KiB region)
//   K1 k_redI (block per (nd,i)): x -> r012,r013,r023,r01,r02,r03,r0
//                                 + atomic r23,r2,r3
//   K2 k_redJ (block per (nd,j)): x -> r123,r12,r13,r1
//   K3 k_mix3: U3[b] = channel-mixed red3 + on-the-fly T2/T1 mixes + bias
//   K4 k_final: out = sum_d c68*x + U012 + U013 + U023 + U123

constexpr size_t R3SZ  = 524288;   // per-a: 16 nd * 32768
constexpr size_t R2SZ  = 16384;    // per-b2: 16 nd * 1024
constexpr size_t R1SZ  = 512;      // per-b1: 16 nd * 32
constexpr size_t R3OFF = 0;        // a: 0=(012) 1=(013) 2=(023) 3=(123)
constexpr size_t R2OFF = R3OFF + 4 * R3SZ;  // b2: 0=(01) 1=(02) 2=(03) 3=(12) 4=(13) 5=(23)
constexpr size_t R1OFF = R2OFF + 6 * R2SZ;  // slots: 0=r2, 1=r3, 2=r0, 3=r1  (r23|r2|r3 contiguous for memset)
constexpr size_t U3OFF = R1OFF + 4 * R1SZ;
// total ws floats: U3OFF + 4*R3SZ = 4294656 (~17.2 MiB)
// axis a1 -> R1 slot: a1=0->2, 1->3, 2->0, 3->1  i.e. slot = (a1+2)&3

// ---------------- K1: all keep-i reductions. block = nd*32 + i ----------------
__global__ __launch_bounds__(256) void k_redI(const float* __restrict__ x,
                                              float* __restrict__ ws) {
    __shared__ float  b012[1024];       // [j*32+k]
    __shared__ float4 p013[1024];       // [(j*4+w)*8 + lq]  (per-wave k-partials)
    __shared__ float4 p03[4][8];        // [w][lq]
    const int b  = blockIdx.x;
    const int i  = b & 31;
    const int nd = b >> 5;
    const int t  = threadIdx.x;
    const int lane = t & 63, w = t >> 6;
    const int k = t >> 3, lq = t & 7;
    const float* xp = x + ((size_t)nd << 20) + ((size_t)i << 15) + t * 4;

    float4 acc = {0.f, 0.f, 0.f, 0.f};
    #pragma unroll 8
    for (int j = 0; j < 32; ++j) {
        float4 v = *(const float4*)(xp + j * 1024);
        acc.x += v.x; acc.y += v.y; acc.z += v.z; acc.w += v.w;   // r023 acc
        // r012[j,k]: sum over l = hsum + butterfly over lq bits
        float h = v.x + v.y + v.z + v.w;
        h += __shfl_xor(h, 1); h += __shfl_xor(h, 2); h += __shfl_xor(h, 4);
        if (lq == 0) b012[j * 32 + k] = h;
        // r013[j,l] per-wave k-partial: butterfly over k bits 3..5
        v.x += __shfl_xor(v.x, 8);  v.y += __shfl_xor(v.y, 8);
        v.z += __shfl_xor(v.z, 8);  v.w += __shfl_xor(v.w, 8);
        v.x += __shfl_xor(v.x, 16); v.y += __shfl_xor(v.y, 16);
        v.z += __shfl_xor(v.z, 16); v.w += __shfl_xor(v.w, 16);
        v.x += __shfl_xor(v.x, 32); v.y += __shfl_xor(v.y, 32);
        v.z += __shfl_xor(v.z, 32); v.w += __shfl_xor(v.w, 32);
        if (lane < 8) p013[(j * 4 + w) * 8 + lane] = v;
    }
    const size_t ndh = (size_t)nd << 15;
    // r023 write + r23 atomics
    *(float4*)(ws + R3OFF + 2 * R3SZ + ndh + ((size_t)i << 10) + t * 4) = acc;
    float* r23p = ws + R2OFF + 5 * R2SZ + nd * 1024 + t * 4;
    unsafeAtomicAdd(r23p + 0, acc.x);
    unsafeAtomicAdd(r23p + 1, acc.y);
    unsafeAtomicAdd(r23p + 2, acc.z);
    unsafeAtomicAdd(r23p + 3, acc.w);
    // r02[i,k] + r2 atomic
    float h2 = acc.x + acc.y + acc.z + acc.w;
    h2 += __shfl_xor(h2, 1); h2 += __shfl_xor(h2, 2); h2 += __shfl_xor(h2, 4);
    if (lq == 0) {
        ws[R2OFF + 1 * R2SZ + nd * 1024 + i * 32 + k] = h2;
        unsafeAtomicAdd(ws + R1OFF + 0 * R1SZ + nd * 32 + k, h2);
    }
    // r03 per-wave partial
    acc.x += __shfl_xor(acc.x, 8);  acc.y += __shfl_xor(acc.y, 8);
    acc.z += __shfl_xor(acc.z, 8);  acc.w += __shfl_xor(acc.w, 8);
    acc.x += __shfl_xor(acc.x, 16); acc.y += __shfl_xor(acc.y, 16);
    acc.z += __shfl_xor(acc.z, 16); acc.w += __shfl_xor(acc.w, 16);
    acc.x += __shfl_xor(acc.x, 32); acc.y += __shfl_xor(acc.y, 32);
    acc.z += __shfl_xor(acc.z, 32); acc.w += __shfl_xor(acc.w, 32);
    if (lane < 8) p03[w][lane] = acc;
    __syncthreads();
    // r012 write (from LDS, coalesced)
    *(float4*)(ws + R3OFF + ndh + ((size_t)i << 10) + t * 4) = *(float4*)(b012 + t * 4);
    // r013 write: combine 4 wave-partials
    {
        const int jj = t >> 3, ql = t & 7;
        float4 s0 = p013[(jj * 4 + 0) * 8 + ql];
        float4 s1 = p013[(jj * 4 + 1) * 8 + ql];
        float4 s2 = p013[(jj * 4 + 2) * 8 + ql];
        float4 s3 = p013[(jj * 4 + 3) * 8 + ql];
        float4 s;
        s.x = s0.x + s1.x + s2.x + s3.x;
        s.y = s0.y + s1.y + s2.y + s3.y;
        s.z = s0.z + s1.z + s2.z + s3.z;
        s.w = s0.w + s1.w + s2.w + s3.w;
        *(float4*)(ws + R3OFF + R3SZ + ndh + ((size_t)i << 10) + t * 4) = s;
    }
    // r01[i,j]
    if (t < 32) {
        float ssum = 0.f;
        #pragma unroll
        for (int m = 0; m < 32; ++m) ssum += b012[t * 32 + ((m + t) & 31)];
        ws[R2OFF + 0 * R2SZ + nd * 1024 + i * 32 + t] = ssum;
    }
    // r03[i,l] + r3 atomic + r0[i]
    if (t < 8) {
        float4 g0 = p03[0][t], g1 = p03[1][t], g2 = p03[2][t], g3 = p03[3][t];
        float4 g;
        g.x = g0.x + g1.x + g2.x + g3.x;
        g.y = g0.y + g1.y + g2.y + g3.y;
        g.z = g0.z + g1.z + g2.z + g3.z;
        g.w = g0.w + g1.w + g2.w + g3.w;
        *(float4*)(ws + R2OFF + 2 * R2SZ + nd * 1024 + i * 32 + t * 4) = g;
        float* r3p = ws + R1OFF + 1 * R1SZ + nd * 32 + t * 4;
        unsafeAtomicAdd(r3p + 0, g.x);
        unsafeAtomicAdd(r3p + 1, g.y);
        unsafeAtomicAdd(r3p + 2, g.z);
        unsafeAtomicAdd(r3p + 3, g.w);
        float gs = g.x + g.y + g.z + g.w;
        gs += __shfl_xor(gs, 1); gs += __shfl_xor(gs, 2); gs += __shfl_xor(gs, 4);
        if (t == 0) ws[R1OFF + 2 * R1SZ + nd * 32 + i] = gs;
    }
}

// ---------------- K2: r123, r12, r13, r1. block = nd*32 + j ----------------
__global__ __launch_bounds__(256) void k_redJ(const float* __restrict__ x,
                                              float* __restrict__ ws) {
    __shared__ float4 p13[4][8];
    const int b  = blockIdx.x;
    const int j  = b & 31;
    const int nd = b >> 5;
    const int t  = threadIdx.x;
    const int lane = t & 63, w = t >> 6;
    const int k = t >> 3, lq = t & 7;
    const float* xp = x + ((size_t)nd << 20) + ((size_t)j << 10) + t * 4;

    float4 acc = {0.f, 0.f, 0.f, 0.f};
    #pragma unroll 8
    for (int i = 0; i < 32; ++i) {
        float4 v = *(const float4*)(xp + ((size_t)i << 15));
        acc.x += v.x; acc.y += v.y; acc.z += v.z; acc.w += v.w;
    }
    *(float4*)(ws + R3OFF + 3 * R3SZ + ((size_t)nd << 15) + ((size_t)j << 10) + t * 4) = acc;
    // r12[j,k]
    float h = acc.x + acc.y + acc.z + acc.w;
    h += __shfl_xor(h, 1); h += __shfl_xor(h, 2); h += __shfl_xor(h, 4);
    if (lq == 0) ws[R2OFF + 3 * R2SZ + nd * 1024 + j * 32 + k] = h;
    // r13 per-wave partial
    acc.x += __shfl_xor(acc.x, 8);  acc.y += __shfl_xor(acc.y, 8);
    acc.z += __shfl_xor(acc.z, 8);  acc.w += __shfl_xor(acc.w, 8);
    acc.x += __shfl_xor(acc.x, 16); acc.y += __shfl_xor(acc.y, 16);
    acc.z += __shfl_xor(acc.z, 16); acc.w += __shfl_xor(acc.w, 16);
    acc.x += __shfl_xor(acc.x, 32); acc.y += __shfl_xor(acc.y, 32);
    acc.z += __shfl_xor(acc.z, 32); acc.w += __shfl_xor(acc.w, 32);
    if (lane < 8) p13[w][lane] = acc;
    __syncthreads();
    if (t < 8) {
        float4 g0 = p13[0][t], g1 = p13[1][t], g2 = p13[2][t], g3 = p13[3][t];
        float4 g;
        g.x = g0.x + g1.x + g2.x + g3.x;
        g.y = g0.y + g1.y + g2.y + g3.y;
        g.z = g0.z + g1.z + g2.z + g3.z;
        g.w = g0.w + g1.w + g2.w + g3.w;
        *(float4*)(ws + R2OFF + 4 * R2SZ + nd * 1024 + j * 32 + t * 4) = g;
        float gs = g.x + g.y + g.z + g.w;
        gs += __shfl_xor(gs, 1); gs += __shfl_xor(gs, 2); gs += __shfl_xor(gs, 4);
        if (t == 0) ws[R1OFF + 3 * R1SZ + nd * 32 + j] = gs;
    }
}

// ---------------- K3: U3[b] = mixed red3 + on-the-fly T2/T1 + bias ----------------
__global__ __launch_bounds__(256) void k_mix3(const float* __restrict__ coefs,
                                              const float* __restrict__ bias,
                                              float* __restrict__ ws) {
    __shared__ float cs[4416];
    __shared__ float bs[8];
    for (int idx = threadIdx.x; idx < 4416; idx += 256) cs[idx] = coefs[idx];
    if (threadIdx.x < 8) bs[threadIdx.x] = bias[threadIdx.x];
    __syncthreads();
    const int blk = blockIdx.x;         // 512 = n(1) | soh(1) | cb(7)
    const int cb  = blk & 127;
    const int soh = (blk >> 7) & 1;
    const int n   = blk >> 8;
    const int c   = cb * 256 + threadIdx.x;
    const int p1 = c >> 10, p2 = (c >> 5) & 31, p3 = c & 31;
    const int q01 = p1 * 32 + p2, qA = p1 * 32 + p3, qB = p2 * 32 + p3;
    const int nd0 = n * 8;

    // T2 values: t2[b2][s]; b2 point = (p1,p2) for 0, (p1,p3) for 1,2, (p2,p3) for 3,4,5
    float t2[6][4] = {{0.f}};
    #pragma unroll
    for (int a2 = 0; a2 < 6; ++a2) {
        const float* r2a = ws + R2OFF + (size_t)a2 * R2SZ + (size_t)nd0 * 1024;
        #pragma unroll
        for (int d = 0; d < 8; ++d) {
            const float* rr = r2a + d * 1024;
            const float v01 = rr[q01], vA = rr[qA], vB = rr[qB];
            const float* cc = cs + (d * 8 + soh * 4) * 69 + 16 + a2 * 6;
            #pragma unroll
            for (int s = 0; s < 4; ++s) {
                const float* c2 = cc + s * 69;
                t2[0][s] += c2[0] * v01;
                t2[1][s] += c2[1] * vA;
                t2[2][s] += c2[2] * vA;
                t2[3][s] += c2[3] * vB;
                t2[4][s] += c2[4] * vB;
                t2[5][s] += c2[5] * vB;
            }
        }
    }
    // T1 values: t1[b1][s]; points p1,p2,p3,p3. axis a1 -> R1 slot (a1+2)&3
    float t1[4][4] = {{0.f}};
    #pragma unroll
    for (int a1 = 0; a1 < 4; ++a1) {
        const float* r1a = ws + R1OFF + (size_t)((a1 + 2) & 3) * R1SZ + (size_t)nd0 * 32;
        #pragma unroll
        for (int d = 0; d < 8; ++d) {
            const float* rr = r1a + d * 32;
            const float u1 = rr[p1], u2 = rr[p2], u3 = rr[p3];
            const float* cc = cs + (d * 8 + soh * 4) * 69 + a1 * 4;
            #pragma unroll
            for (int s = 0; s < 4; ++s) {
                const float* c1 = cc + s * 69;
                t1[0][s] += c1[0] * u1;
                t1[1][s] += c1[1] * u2;
                t1[2][s] += c1[2] * u3;
                t1[3][s] += c1[3] * u3;
            }
        }
    }
    // red3 values
    float v[4][8];
    #pragma unroll
    for (int a = 0; a < 4; ++a)
        #pragma unroll
        for (int d = 0; d < 8; ++d)
            v[a][d] = ws[R3OFF + (size_t)a * R3SZ + (size_t)(nd0 + d) * 32768 + c];
    #pragma unroll
    for (int b = 0; b < 4; ++b) {
        #pragma unroll
        for (int s = 0; s < 4; ++s) {
            const int so = soh * 4 + s;
            float sum = 0.f;
            #pragma unroll
            for (int a = 0; a < 4; ++a)
                #pragma unroll
                for (int d = 0; d < 8; ++d)
                    sum += cs[(d * 8 + so) * 69 + 52 + a * 4 + b] * v[a][d];
            if (b == 0) {
                sum += t2[0][s] + t2[1][s] + t2[3][s]
                     + t1[0][s] + t1[1][s] + t1[2][s] + bs[so];
            } else if (b == 1) {
                sum += t2[2][s] + t2[4][s] + t1[3][s];
            } else if (b == 2) {
                sum += t2[5][s];
            }
            ws[U3OFF + (size_t)b * R3SZ + (size_t)(nd0 + so) * 32768 + c] = sum;
        }
    }
}

// ---------------- K4: final broadcast-add + s=4 channel mix ----------------
__global__ __launch_bounds__(256) void k_final(const float* __restrict__ x,
                                               const float* __restrict__ coefs,
                                               const float* __restrict__ ws,
                                               float* __restrict__ out) {
    __shared__ float c68[64];
    if (threadIdx.x < 64) c68[threadIdx.x] = coefs[threadIdx.x * 69 + 68];
    __syncthreads();
    const int b = blockIdx.x;           // (n*32+i)*32 + j
    const int j = b & 31;
    const int i = (b >> 5) & 31;
    const int n = b >> 10;
    const int t = threadIdx.x;
    const int k = t >> 3, lq = t & 7;

    float4 xv[8];
    const float* xb = x + ((size_t)n << 23) + ((size_t)i << 15) + j * 1024 + k * 32 + lq * 4;
    #pragma unroll
    for (int d = 0; d < 8; ++d) xv[d] = *(const float4*)(xb + ((size_t)d << 20));

    const float* U = ws + U3OFF;
    const size_t c012 = (size_t)i * 1024 + j * 32 + k;
    const size_t c013 = (size_t)i * 1024 + j * 32 + lq * 4;
    const size_t c023 = (size_t)i * 1024 + k * 32 + lq * 4;
    const size_t c123 = (size_t)j * 1024 + k * 32 + lq * 4;

    #pragma unroll
    for (int so = 0; so < 8; ++so) {
        const size_t nso = (size_t)(n * 8 + so) << 15;
        const float  u0 = U[0 * R3SZ + nso + c012];
        const float4 u1 = *(const float4*)(U + 1 * R3SZ + nso + c013);
        const float4 u2 = *(const float4*)(U + 2 * R3SZ + nso + c023);
        const float4 u3 = *(const float4*)(U + 3 * R3SZ + nso + c123);
        float4 acc;
        acc.x = u0 + u1.x + u2.x + u3.x;
        acc.y = u0 + u1.y + u2.y + u3.y;
        acc.z = u0 + u1.z + u2.z + u3.z;
        acc.w = u0 + u1.w + u2.w + u3.w;
        #pragma unroll
        for (int d = 0; d < 8; ++d) {
            const float w = c68[d * 8 + so];
            acc.x += w * xv[d].x; acc.y += w * xv[d].y;
            acc.z += w * xv[d].z; acc.w += w * xv[d].w;
        }
        *(float4*)(out + ((size_t)(n * 8 + so) << 20) + ((size_t)i << 15)
                   + j * 1024 + k * 32 + lq * 4) = acc;
    }
}

extern "C" void kernel_launch(void* const* d_in, const int* in_sizes, int n_in,
                              void* d_out, int out_size, void* d_ws, size_t ws_size,
                              hipStream_t stream) {
    const float* x     = (const float*)d_in[0];
    const float* coefs = (const float*)d_in[1];
    const float* bias  = (const float*)d_in[2];
    float* out = (float*)d_out;
    float* ws  = (float*)d_ws;

    // zero atomic targets: r23 | r2 | r3 (contiguous, 17408 floats)
    hipMemsetAsync(ws + R2OFF + 5 * R2SZ, 0, 17408 * sizeof(float), stream);

    hipLaunchKernelGGL(k_redI,  dim3(512),  dim3(256), 0, stream, x, ws);
    hipLaunchKernelGGL(k_redJ,  dim3(512),  dim3(256), 0, stream, x, ws);
    hipLaunchKernelGGL(k_mix3,  dim3(512),  dim3(256), 0, stream, coefs, bias, ws);
    hipLaunchKernelGGL(k_final, dim3(2048), dim3(256), 0, stream, x, coefs, ws, out);
}